// Round 18
// baseline (92.046 us; speedup 1.0000x reference)
//
#include <hip/hip_runtime.h>
#include <hip/hip_fp16.h>

// Batched 10-qubit statevector simulator — TWO samples per 64-lane wave.
// Per sample: 1024 complex amps as f16x2 (re,im), 16 regs/lane;
// s = (r<<6)|lane; qubit q <-> bit (9-q):
//   qubits 0..3 -> register-index bits, qubits 4..9 -> lane bits.
// R14/R15: f16x2 packed state + packed math (steady ~38.5us, VALUBusy 62%,
//   DS ~20%, occupancy grid-capped at 4 waves/SIMD).
// R16: op_sel asm + precomputed packed coeffs — NEUTRAL: instruction count
//   is no longer the binding constraint; residual is dependency/waitcnt
//   latency that 4 waves/SIMD can't hide.
// R17: 2 SAMPLES PER WAVE (cA+cB, 2048 waves = 2/SIMD). Total VALU/CU
//   unchanged; every stall in A's dependent chain is filled by B's fully
//   independent stream (ILP replaces grid-capped TLP). Opposite of R8's
//   failed split (no barriers, no coupling).
// Carried: lane-parallel coeffs + readlane; fused ring-chain bperm; DPP
//   masks 1,2,8 + 2-DPP mask 4; layer-0 product construction; final ring
//   folded into epilogue parities; fp32 coeffs & epilogue.

constexpr int NQ  = 10;
constexpr int NL  = 5;
constexpr int OBS = 10;

typedef float f2 __attribute__((ext_vector_type(2)));

__device__ __forceinline__ float readlane_f(float v, int l) {
    return __int_as_float(__builtin_amdgcn_readlane(__float_as_int(v), l));
}
__device__ __forceinline__ int h2i(__half2 v) { int i; __builtin_memcpy(&i, &v, 4); return i; }
__device__ __forceinline__ __half2 i2h(int i) { __half2 v; __builtin_memcpy(&v, &i, 4); return v; }

__device__ __forceinline__ __half2 bperm_h2(int byte_addr, __half2 v) {
    return i2h(__builtin_amdgcn_ds_bpermute(byte_addr, h2i(v)));
}
template <int CTRL>
__device__ __forceinline__ __half2 dpp_h2(__half2 v) {
    return i2h(__builtin_amdgcn_update_dpp(0, h2i(v), CTRL, 0xF, 0xF, true));
}
// xor-exchange across lanes; M compile-time -> branches fold.
__device__ __forceinline__ __half2 xor_lane(__half2 v, int M, int a16, int a32) {
    switch (M) {
    case 1:  return dpp_h2<0xB1>(v);                // quad_perm [1,0,3,2]
    case 2:  return dpp_h2<0x4E>(v);                // quad_perm [2,3,0,1]
    case 8:  return dpp_h2<0x128>(v);               // row_ror:8 == lane^8
    case 4:  return dpp_h2<0x141>(dpp_h2<0x1B>(v)); // xor3 ∘ xor7 = xor4
    case 16: return bperm_h2(a16, v);
    default: return bperm_h2(a32, v);               // 32
    }
}
__device__ __forceinline__ int xor_lane_i(int v, int M, int a16, int a32) {
    switch (M) {
    case 1:  return __builtin_amdgcn_update_dpp(0, v, 0xB1, 0xF, 0xF, true);
    case 2:  return __builtin_amdgcn_update_dpp(0, v, 0x4E, 0xF, 0xF, true);
    case 8:  return __builtin_amdgcn_update_dpp(0, v, 0x128, 0xF, 0xF, true);
    case 4:  return __builtin_amdgcn_update_dpp(0,
                 __builtin_amdgcn_update_dpp(0, v, 0x1B, 0xF, 0xF, true),
                 0x141, 0xF, 0xF, true);
    case 16: return __builtin_amdgcn_ds_bpermute(a16, v);
    default: return __builtin_amdgcn_ds_bpermute(a32, v);
    }
}
__device__ __forceinline__ __half2 swap_h2(__half2 v) { return __lowhigh2highlow(v); }
// 4-term packed complex-pair accumulation: a*b + c*d + e*f + g*h
__device__ __forceinline__ __half2 acc4(__half2 a, __half2 b, __half2 c, __half2 d,
                                        __half2 e, __half2 f, __half2 g, __half2 h) {
    return __hfma2(a, b, __hfma2(c, d, __hfma2(e, f, __hmul2(g, h))));
}

// fused-gate SU(2) column coefficients for (lyr, q) of one sample
__device__ __forceinline__ void gate_coeffs(const float* __restrict__ xrow,
                                            const float* __restrict__ isc,
                                            const float* __restrict__ w,
                                            int lyr, int q,
                                            float& UR, float& UI, float& VR, float& VI) {
    const float xq    = xrow[q];
    const float alpha = isc[lyr * 2 * NQ + q]      * xq;
    const float beta  = isc[lyr * 2 * NQ + NQ + q] * xq;
    const float gamma = w[lyr * 2 * NQ + q];
    const float delta = w[lyr * 2 * NQ + NQ + q];
    float sa, ca, sp, cp, sd, cd;
    __sincosf(0.5f * alpha,          &sa, &ca);
    __sincosf(0.5f * (beta + gamma), &sp, &cp);
    __sincosf(0.5f * delta,          &sd, &cd);
    const float A = cd * ca, Bt = sd * sa;
    const float C = cd * sa, D  = sd * ca;
    UR = (A - Bt) * cp;
    UI = -(A + Bt) * sp;
    VR = (C + D) * cp;
    VI = (C - D) * sp;
}

// layer-0 product-state construction: amp(s) = prod_q (bit_q ? v_q : u_q)
__device__ __forceinline__ void build_state(__half2* c, int lane,
                                            float cUR, float cUI,
                                            float cVR, float cVI) {
    float Lr = 1.f, Li = 0.f;
#pragma unroll
    for (int q = 4; q < 10; ++q) {
        const float ur = readlane_f(cUR, q), ui = readlane_f(cUI, q);
        const float vr = readlane_f(cVR, q), vi = readlane_f(cVI, q);
        const int M = 1 << (9 - q);
        const float fr = (lane & M) ? vr : ur;
        const float fi = (lane & M) ? vi : ui;
        const float nr = Lr * fr - Li * fi;
        const float ni = Lr * fi + Li * fr;
        Lr = nr; Li = ni;
    }
    f2 cf[16];
    cf[0] = (f2){Lr, Li};
#pragma unroll
    for (int r = 1; r < 16; ++r) cf[r] = (f2){0.f, 0.f};
#pragma unroll
    for (int q = 3; q >= 0; --q) {
        const int m = 1 << (3 - q);
        const float ur = readlane_f(cUR, q), ui = readlane_f(cUI, q);
        const float vr = readlane_f(cVR, q), vi = readlane_f(cVI, q);
#pragma unroll
        for (int r0 = 0; r0 < 16; ++r0) {
            if (r0 >= m) continue;
            const f2 s = cf[r0];
            cf[r0 | m] = (f2){ s.x*vr - s.y*vi, s.x*vi + s.y*vr };
            cf[r0]     = (f2){ s.x*ur - s.y*ui, s.x*ui + s.y*ur };
        }
    }
#pragma unroll
    for (int r = 0; r < 16; ++r) c[r] = __floats2half2_rn(cf[r].x, cf[r].y);
}

__global__ __launch_bounds__(256, 2) void qsim_kernel(
    const float* __restrict__ x,       // (B, 10)
    const float* __restrict__ isc,     // (5, 20)
    const float* __restrict__ w,       // (5, 20)
    const float* __restrict__ oscale,  // (4)
    float* __restrict__ out,           // (B, 4)
    int halfB)
{
    const int lane = threadIdx.x & 63;
    const int wv   = (blockIdx.x * blockDim.x + threadIdx.x) >> 6;
    if (wv >= halfB) return;
    const int widA = 2 * wv, widB = 2 * wv + 1;

    // ---- lane-parallel gate-coefficient computation, both samples ----
    float aUR, aUI, aVR, aVI, bUR, bUI, bVR, bVI;
    {
        const int g   = (lane < 50) ? lane : 49;
        const int q   = g % 10;
        const int lyr = g / 10;
        gate_coeffs(x + widA * OBS, isc, w, lyr, q, aUR, aUI, aVR, aVI);
        gate_coeffs(x + widB * OBS, isc, w, lyr, q, bUR, bUI, bVR, bVI);
    }

    // hoisted bpermute byte-addresses (loop-invariant)
    const int a16 = (lane ^ 16) * 4;
    const int a32 = (lane ^ 32) * 4;
    const int cnot_src  = (lane ^ (lane >> 1));
    const int addr_even = cnot_src * 4;            // r bit0 == 0
    const int addr_odd  = (cnot_src ^ 32) * 4;     // r bit0 == 1 (CNOT(3,4))

    __half2 cA[16], cB[16];
    build_state(cA, lane, aUR, aUI, aVR, aVI);
    build_state(cB, lane, bUR, bUI, bVR, bVI);

#define SWAPR(arr, i, j) { __half2 _t = arr[i]; arr[i] = arr[j]; arr[j] = _t; }

    for (int layer = 0; layer < NL; ++layer) {
        const int base = layer * NQ;   // wave-uniform

        // ---- fused single-qubit unitaries (layer 0 done by construction) ----
        if (layer > 0) {
#pragma unroll
            for (int q = 0; q < NQ; ++q) {
                const float Aur = readlane_f(aUR, base + q);
                const float Aui = readlane_f(aUI, base + q);
                const float Avr = readlane_f(aVR, base + q);
                const float Avi = readlane_f(aVI, base + q);
                const float Bur = readlane_f(bUR, base + q);
                const float Bui = readlane_f(bUI, base + q);
                const float Bvr = readlane_f(bVR, base + q);
                const float Bvi = readlane_f(bVI, base + q);

                if (q < 4) {
                    // register-bit qubit: pair stride m inside the lane.
                    const __half2 AkUU  = __floats2half2_rn(Aur, Aur);
                    const __half2 AkUIm = __floats2half2_rn(-Aui, Aui);
                    const __half2 AkVVn = __floats2half2_rn(-Avr, -Avr);
                    const __half2 AkVV  = __floats2half2_rn(Avr, Avr);
                    const __half2 AkVIm = __floats2half2_rn(-Avi, Avi);
                    const __half2 AkUIp = __floats2half2_rn(Aui, -Aui);
                    const __half2 BkUU  = __floats2half2_rn(Bur, Bur);
                    const __half2 BkUIm = __floats2half2_rn(-Bui, Bui);
                    const __half2 BkVVn = __floats2half2_rn(-Bvr, -Bvr);
                    const __half2 BkVV  = __floats2half2_rn(Bvr, Bvr);
                    const __half2 BkVIm = __floats2half2_rn(-Bvi, Bvi);
                    const __half2 BkUIp = __floats2half2_rn(Bui, -Bui);
                    const int m = 1 << (3 - q);
#pragma unroll
                    for (int r0 = 0; r0 < 16; ++r0) {
                        if (r0 & m) continue;
                        const int r1 = r0 | m;
                        const __half2 a0 = cA[r0], a1 = cA[r1];
                        const __half2 b0 = cB[r0], b1 = cB[r1];
                        const __half2 a0s = swap_h2(a0), a1s = swap_h2(a1);
                        const __half2 b0s = swap_h2(b0), b1s = swap_h2(b1);
                        cA[r0] = acc4(AkUU, a0, AkUIm, a0s, AkVVn, a1, AkVIm, a1s);
                        cB[r0] = acc4(BkUU, b0, BkUIm, b0s, BkVVn, b1, BkVIm, b1s);
                        cA[r1] = acc4(AkVV, a0, AkVIm, a0s, AkUU,  a1, AkUIp, a1s);
                        cB[r1] = acc4(BkVV, b0, BkVIm, b0s, BkUU,  b1, BkUIp, b1s);
                    }
                } else {
                    // lane-bit qubit: butterfly exchange with lane^M.
                    const int  M   = 1 << (9 - q);
                    const bool bit = (lane & M) != 0;
                    const float APi = bit ? -Aui : Aui;
                    const float AQr = bit ?  Avr : -Avr;
                    const float BPi = bit ? -Bui : Bui;
                    const float BQr = bit ?  Bvr : -Bvr;
                    const __half2 AkUU = __floats2half2_rn(Aur, Aur);
                    const __half2 AkPI = __floats2half2_rn(-APi, APi);
                    const __half2 AkQR = __floats2half2_rn(AQr, AQr);
                    const __half2 AkVI = __floats2half2_rn(-Avi, Avi);
                    const __half2 BkUU = __floats2half2_rn(Bur, Bur);
                    const __half2 BkPI = __floats2half2_rn(-BPi, BPi);
                    const __half2 BkQR = __floats2half2_rn(BQr, BQr);
                    const __half2 BkVI = __floats2half2_rn(-Bvi, Bvi);
#pragma unroll
                    for (int r = 0; r < 16; ++r) {
                        const __half2 mvA = cA[r];
                        const __half2 mvB = cB[r];
                        const __half2 pvA = xor_lane(mvA, M, a16, a32);
                        const __half2 pvB = xor_lane(mvB, M, a16, a32);
                        cA[r] = acc4(AkUU, mvA, AkPI, swap_h2(mvA), AkQR, pvA, AkVI, swap_h2(pvA));
                        cB[r] = acc4(BkUU, mvB, BkPI, swap_h2(mvB), BkQR, pvB, BkVI, swap_h2(pvB));
                    }
                }
            }
        }

        // ---- CNOT ring (skipped on last layer; folded into epilogue) ----
        if (layer < NL - 1) {
            // CNOT(0,1): ctrl r-bit3, tgt r-bit2 -> register swap
            SWAPR(cA, 8, 12) SWAPR(cA, 9, 13) SWAPR(cA, 10, 14) SWAPR(cA, 11, 15)
            SWAPR(cB, 8, 12) SWAPR(cB, 9, 13) SWAPR(cB, 10, 14) SWAPR(cB, 11, 15)
            // CNOT(1,2): ctrl r-bit2, tgt r-bit1
            SWAPR(cA, 4, 6)  SWAPR(cA, 5, 7)  SWAPR(cA, 12, 14) SWAPR(cA, 13, 15)
            SWAPR(cB, 4, 6)  SWAPR(cB, 5, 7)  SWAPR(cB, 12, 14) SWAPR(cB, 13, 15)
            // CNOT(2,3): ctrl r-bit1, tgt r-bit0
            SWAPR(cA, 2, 3)  SWAPR(cA, 6, 7)  SWAPR(cA, 10, 11) SWAPR(cA, 14, 15)
            SWAPR(cB, 2, 3)  SWAPR(cB, 6, 7)  SWAPR(cB, 10, 11) SWAPR(cB, 14, 15)
            // CNOT(3,4)..(8,9) fused: ONE bpermute per amplitude (f16x2).
#pragma unroll
            for (int r = 0; r < 16; ++r) {
                const int addr = (r & 1) ? addr_odd : addr_even;
                cA[r] = bperm_h2(addr, cA[r]);
                cB[r] = bperm_h2(addr, cB[r]);
            }
            // CNOT(9,0): ctrl lane-bit0, tgt r-bit3 -> cond register swap
            const bool ctl = (lane & 1) != 0;
#pragma unroll
            for (int r = 0; r < 8; ++r) {
                const __half2 tA0 = cA[r], tA1 = cA[r + 8];
                cA[r]     = ctl ? tA1 : tA0;
                cA[r + 8] = ctl ? tA0 : tA1;
                const __half2 tB0 = cB[r], tB1 = cB[r + 8];
                cB[r]     = ctl ? tB1 : tB0;
                cB[r + 8] = ctl ? tB0 : tB1;
            }
        }
    }

    // ---- epilogue (fp32): <Z_i> after the (virtual) final ring ----
    // (Cb)_0 = q1+..+q9 -> reg bits r2,r1,r0 + all 6 lane bits
    // (Cb)_1 = q0+q1 -> r3,r2 ; (Cb)_2 -> r3,r2,r1 ; (Cb)_3 -> r3..r0
    const float sL = (__popc(lane) & 1) ? -1.f : 1.f;
    float zA0 = 0.f, zA1 = 0.f, zA2 = 0.f, zA3 = 0.f;
    float zB0 = 0.f, zB1 = 0.f, zB2 = 0.f, zB3 = 0.f;
#pragma unroll
    for (int r = 0; r < 16; ++r) {
        const float ar = __low2float(cA[r]), ai = __high2float(cA[r]);
        const float br = __low2float(cB[r]), bi = __high2float(cB[r]);
        const float pA = ar * ar + ai * ai;
        const float pB = br * br + bi * bi;
        const float pAl = sL * pA, pBl = sL * pB;
        const bool n0 = __popc(r & 7)  & 1;
        const bool n1 = __popc(r & 12) & 1;
        const bool n2 = __popc(r & 14) & 1;
        const bool n3 = __popc(r & 15) & 1;
        zA0 += n0 ? -pAl : pAl;  zB0 += n0 ? -pBl : pBl;
        zA1 += n1 ? -pA  : pA;   zB1 += n1 ? -pB  : pB;
        zA2 += n2 ? -pA  : pA;   zB2 += n2 ? -pB  : pB;
        zA3 += n3 ? -pA  : pA;   zB3 += n3 ? -pB  : pB;
    }
#pragma unroll
    for (int m = 1; m < 64; m <<= 1) {
        zA0 += __int_as_float(xor_lane_i(__float_as_int(zA0), m, a16, a32));
        zB0 += __int_as_float(xor_lane_i(__float_as_int(zB0), m, a16, a32));
        zA1 += __int_as_float(xor_lane_i(__float_as_int(zA1), m, a16, a32));
        zB1 += __int_as_float(xor_lane_i(__float_as_int(zB1), m, a16, a32));
        zA2 += __int_as_float(xor_lane_i(__float_as_int(zA2), m, a16, a32));
        zB2 += __int_as_float(xor_lane_i(__float_as_int(zB2), m, a16, a32));
        zA3 += __int_as_float(xor_lane_i(__float_as_int(zA3), m, a16, a32));
        zB3 += __int_as_float(xor_lane_i(__float_as_int(zB3), m, a16, a32));
    }
    if (lane == 0) {
        out[widA * 4 + 0] = zA0 * oscale[0];
        out[widA * 4 + 1] = zA1 * oscale[1];
        out[widA * 4 + 2] = zA2 * oscale[2];
        out[widA * 4 + 3] = zA3 * oscale[3];
        out[widB * 4 + 0] = zB0 * oscale[0];
        out[widB * 4 + 1] = zB1 * oscale[1];
        out[widB * 4 + 2] = zB2 * oscale[2];
        out[widB * 4 + 3] = zB3 * oscale[3];
    }
#undef SWAPR
}

extern "C" void kernel_launch(void* const* d_in, const int* in_sizes, int n_in,
                              void* d_out, int out_size, void* d_ws, size_t ws_size,
                              hipStream_t stream) {
    const float* x      = (const float*)d_in[0];
    const float* isc    = (const float*)d_in[1];
    const float* w      = (const float*)d_in[2];
    const float* oscale = (const float*)d_in[3];
    float* out = (float*)d_out;

    const int B     = in_sizes[0] / OBS;         // 4096
    const int halfB = B / 2;                     // 2048 waves, 2 samples each
    const int threads = 256;                     // 4 waves -> 8 samples per block
    const int blocks = (halfB * 64 + threads - 1) / threads;
    qsim_kernel<<<blocks, threads, 0, stream>>>(x, isc, w, oscale, out, halfB);
}

// Round 19
// 88.204 us; speedup vs baseline: 1.0436x; 1.0436x over previous
//
#include <hip/hip_runtime.h>

// Batched 10-qubit statevector simulator — one 64-lane wave per sample.
// State: 1024 complex amps; s = (r<<6)|lane; qubit q <-> bit (9-q):
//   qubits 0..3 -> register-index bits (16 regs per lane)
//   qubits 4..9 -> lane bits (butterfly exchanges)
// R14 FINAL (best: 88.8us top-line, steady ~38.5us): state packed as f16x2
//   (re,im) in one VGPR per amplitude — every cross-lane op (DPP/bperm/
//   cndmask) moves the whole complex amplitude in ONE 32-bit op, and the
//   packed _Float16 vector math compiles to full-rate v_pk_fma_f16.
//   Coefficients fp32 (sincos + readlane broadcast); layer-0 construction
//   and epilogue accumulate fp32. absmax 9.8e-4 < 3.59e-3 threshold.
// Ladder: 137us (R0 naive-reg) -> 78 (lane-parallel coeffs via readlane +
//   launch_bounds(256,4)) -> 64 (packed f32 VOP3P) -> 48 (DPP for masks
//   1,2,8) -> 44.8 (layer-0 product construction + ring-4 folded into
//   epilogue parities) -> 41.8 (mask-4 as 2-DPP chain) -> 38.5 (f16x2).
// Falsified alternatives (all neutral or worse): extra waves/sample (R8),
//   DS phase staggering (R11), ring folding into gate coeffs (R12), rolled
//   layer loop (R13), __hfma2 forcing (R15), op_sel inline asm + packed
//   coeff precompute (R16), 2 samples/wave ILP (R17). Residual structure:
//   ~62% VALU issue, ~22% DS pipe, ~16% waitcnt/scalar — invariant.

constexpr int NQ  = 10;
constexpr int NL  = 5;
constexpr int OBS = 10;

typedef float    f2 __attribute__((ext_vector_type(2)));
typedef _Float16 h2 __attribute__((ext_vector_type(2)));

__device__ __forceinline__ float readlane_f(float v, int l) {
    return __int_as_float(__builtin_amdgcn_readlane(__float_as_int(v), l));
}
__device__ __forceinline__ int h2_to_i(h2 v) { int i; __builtin_memcpy(&i, &v, 4); return i; }
__device__ __forceinline__ h2  i_to_h2(int i) { h2 v; __builtin_memcpy(&v, &i, 4); return v; }

__device__ __forceinline__ h2 bperm_h2(int byte_addr, h2 v) {
    return i_to_h2(__builtin_amdgcn_ds_bpermute(byte_addr, h2_to_i(v)));
}
template <int CTRL>
__device__ __forceinline__ h2 dpp_h2(h2 v) {
    return i_to_h2(__builtin_amdgcn_update_dpp(0, h2_to_i(v), CTRL, 0xF, 0xF, true));
}
// xor-exchange across lanes; M compile-time -> branches fold.
__device__ __forceinline__ h2 xor_lane(h2 v, int M, int a16, int a32) {
    switch (M) {
    case 1:  return dpp_h2<0xB1>(v);               // quad_perm [1,0,3,2]
    case 2:  return dpp_h2<0x4E>(v);               // quad_perm [2,3,0,1]
    case 8:  return dpp_h2<0x128>(v);              // row_ror:8 == lane^8
    case 4:  return dpp_h2<0x141>(dpp_h2<0x1B>(v)); // xor3 ∘ xor7 = xor4
    case 16: return bperm_h2(a16, v);
    default: return bperm_h2(a32, v);              // 32
    }
}
__device__ __forceinline__ h2 mk_h2(float a, float b) {
    h2 r; r.x = (_Float16)a; r.y = (_Float16)b; return r;
}

__global__ __launch_bounds__(256, 4) void qsim_kernel(
    const float* __restrict__ x,       // (B, 10)
    const float* __restrict__ isc,     // (5, 20)
    const float* __restrict__ w,       // (5, 20)
    const float* __restrict__ oscale,  // (4)
    float* __restrict__ out,           // (B, 4)
    int B)
{
    const int lane = threadIdx.x & 63;
    const int wid  = (blockIdx.x * blockDim.x + threadIdx.x) >> 6;
    if (wid >= B) return;

    // ---- lane-parallel gate-coefficient computation (gates 0..49), fp32 ----
    float cUR, cUI, cVR, cVI;
    {
        const int g   = (lane < 50) ? lane : 49;
        const int q   = g % 10;
        const int lyr = g / 10;
        const float xq    = x[wid * OBS + q];
        const float alpha = isc[lyr * 2 * NQ + q]      * xq;
        const float beta  = isc[lyr * 2 * NQ + NQ + q] * xq;
        const float gamma = w[lyr * 2 * NQ + q];
        const float delta = w[lyr * 2 * NQ + NQ + q];
        float sa, ca, sp, cp, sd, cd;
        __sincosf(0.5f * alpha,          &sa, &ca);
        __sincosf(0.5f * (beta + gamma), &sp, &cp);
        __sincosf(0.5f * delta,          &sd, &cd);
        const float A = cd * ca, Bt = sd * sa;
        const float C = cd * sa, D  = sd * ca;
        cUR = (A - Bt) * cp;
        cUI = -(A + Bt) * sp;
        cVR = (C + D) * cp;
        cVI = (C - D) * sp;
    }

    // hoisted bpermute byte-addresses (loop-invariant)
    const int a16 = (lane ^ 16) * 4;
    const int a32 = (lane ^ 32) * 4;
    const int cnot_src  = (lane ^ (lane >> 1));
    const int addr_even = cnot_src * 4;            // r bit0 == 0
    const int addr_odd  = (cnot_src ^ 32) * 4;     // r bit0 == 1 (CNOT(3,4))

    h2 c[16];

    // ===== layer 0: direct product-state construction (fp32 -> f16x2) =====
    // amp(s) = prod_q (bit_q(s) ? v_q : u_q), gate column (u,v)=U|0>.
    {
        float Lr = 1.f, Li = 0.f;
#pragma unroll
        for (int q = 4; q < 10; ++q) {
            const float ur = readlane_f(cUR, q), ui = readlane_f(cUI, q);
            const float vr = readlane_f(cVR, q), vi = readlane_f(cVI, q);
            const int M = 1 << (9 - q);
            const float fr = (lane & M) ? vr : ur;
            const float fi = (lane & M) ? vi : ui;
            const float nr = Lr * fr - Li * fi;
            const float ni = Lr * fi + Li * fr;
            Lr = nr; Li = ni;
        }
        f2 cf[16];
        cf[0] = (f2){Lr, Li};
#pragma unroll
        for (int r = 1; r < 16; ++r) cf[r] = (f2){0.f, 0.f};
#pragma unroll
        for (int q = 3; q >= 0; --q) {
            const int m = 1 << (3 - q);
            const float ur = readlane_f(cUR, q), ui = readlane_f(cUI, q);
            const float vr = readlane_f(cVR, q), vi = readlane_f(cVI, q);
#pragma unroll
            for (int r0 = 0; r0 < 16; ++r0) {
                if (r0 >= m) continue;
                const f2 s = cf[r0];
                cf[r0 | m] = (f2){ s.x*vr - s.y*vi, s.x*vi + s.y*vr };
                cf[r0]     = (f2){ s.x*ur - s.y*ui, s.x*ui + s.y*ur };
            }
        }
#pragma unroll
        for (int r = 0; r < 16; ++r) c[r] = mk_h2(cf[r].x, cf[r].y);
    }

#define SWAPR(i, j) { h2 _t = c[i]; c[i] = c[j]; c[j] = _t; }

    for (int layer = 0; layer < NL; ++layer) {
        const int base = layer * NQ;   // wave-uniform

        // ---- fused single-qubit unitaries (layer 0 done by construction) ----
        if (layer > 0) {
#pragma unroll
            for (int q = 0; q < NQ; ++q) {
                const float ur = readlane_f(cUR, base + q);
                const float ui = readlane_f(cUI, base + q);
                const float vr = readlane_f(cVR, base + q);
                const float vi = readlane_f(cVI, base + q);

                if (q < 4) {
                    // register-bit qubit: pair stride m inside the lane.
                    const h2 kUU  = mk_h2(ur, ur);
                    const h2 kUIm = mk_h2(-ui, ui);
                    const h2 kVVn = mk_h2(-vr, -vr);
                    const h2 kVV  = mk_h2(vr, vr);
                    const h2 kVIm = mk_h2(-vi, vi);
                    const h2 kUIp = mk_h2(ui, -ui);
                    const int m = 1 << (3 - q);
#pragma unroll
                    for (int r0 = 0; r0 < 16; ++r0) {
                        if (r0 & m) continue;
                        const int r1 = r0 | m;
                        const h2 c0 = c[r0], c1 = c[r1];
                        const h2 c0s = c0.yx, c1s = c1.yx;
                        c[r0] = kUU*c0 + kUIm*c0s + kVVn*c1 + kVIm*c1s;
                        c[r1] = kVV*c0 + kVIm*c0s + kUU*c1  + kUIp*c1s;
                    }
                } else {
                    // lane-bit qubit: butterfly exchange with lane^M.
                    const int  M   = 1 << (9 - q);
                    const bool bit = (lane & M) != 0;
                    const float Pi = bit ? -ui : ui;
                    const float Qr = bit ?  vr : -vr;
                    const h2 kUUb = mk_h2(ur, ur);
                    const h2 kPI  = mk_h2(-Pi, Pi);
                    const h2 kQR  = mk_h2(Qr, Qr);
                    const h2 kVIb = mk_h2(-vi, vi);
#pragma unroll
                    for (int r = 0; r < 16; ++r) {
                        const h2 mv = c[r];
                        const h2 pv = xor_lane(mv, M, a16, a32);
                        c[r] = kUUb*mv + kPI*mv.yx + kQR*pv + kVIb*pv.yx;
                    }
                }
            }
        }

        // ---- CNOT ring (skipped on last layer; folded into epilogue) ----
        if (layer < NL - 1) {
            // CNOT(0,1): ctrl r-bit3, tgt r-bit2 -> register swap
            SWAPR(8, 12) SWAPR(9, 13) SWAPR(10, 14) SWAPR(11, 15)
            // CNOT(1,2): ctrl r-bit2, tgt r-bit1
            SWAPR(4, 6)  SWAPR(5, 7)  SWAPR(12, 14) SWAPR(13, 15)
            // CNOT(2,3): ctrl r-bit1, tgt r-bit0
            SWAPR(2, 3)  SWAPR(6, 7)  SWAPR(10, 11) SWAPR(14, 15)
            // CNOT(3,4)..(8,9) fused: ONE bpermute per amplitude (f16x2).
#pragma unroll
            for (int r = 0; r < 16; ++r) {
                const int addr = (r & 1) ? addr_odd : addr_even;
                c[r] = bperm_h2(addr, c[r]);
            }
            // CNOT(9,0): ctrl lane-bit0, tgt r-bit3 -> cond register swap
            const bool ctl = (lane & 1) != 0;
#pragma unroll
            for (int r = 0; r < 8; ++r) {
                const h2 t0 = c[r], t1 = c[r + 8];
                c[r]     = ctl ? t1 : t0;
                c[r + 8] = ctl ? t0 : t1;
            }
        }
    }

    // ---- epilogue (fp32): <Z_i> after the (virtual) final ring ----
    // (Cb)_0 = q1+..+q9 -> reg bits r2,r1,r0 + all 6 lane bits
    // (Cb)_1 = q0+q1 -> r3,r2 ; (Cb)_2 -> r3,r2,r1 ; (Cb)_3 -> r3..r0
    const float sL = (__popc(lane) & 1) ? -1.f : 1.f;
    float z0 = 0.f, z1 = 0.f, z2 = 0.f, z3 = 0.f;
#pragma unroll
    for (int r = 0; r < 16; ++r) {
        const float cr = (float)c[r].x, ci = (float)c[r].y;
        const float pv  = cr * cr + ci * ci;
        const float pvl = sL * pv;
        z0 += (__popc(r & 7)  & 1) ? -pvl : pvl;
        z1 += (__popc(r & 12) & 1) ? -pv  : pv;
        z2 += (__popc(r & 14) & 1) ? -pv  : pv;
        z3 += (__popc(r & 15) & 1) ? -pv  : pv;
    }
    // f32 xor-lane reduction (DPP for 1,2,4,8; bperm for 16,32)
#pragma unroll
    for (int m = 1; m < 64; m <<= 1) {
        if (m == 1)      { z0 += __int_as_float(__builtin_amdgcn_update_dpp(0, __float_as_int(z0), 0xB1, 0xF, 0xF, true));
                           z1 += __int_as_float(__builtin_amdgcn_update_dpp(0, __float_as_int(z1), 0xB1, 0xF, 0xF, true));
                           z2 += __int_as_float(__builtin_amdgcn_update_dpp(0, __float_as_int(z2), 0xB1, 0xF, 0xF, true));
                           z3 += __int_as_float(__builtin_amdgcn_update_dpp(0, __float_as_int(z3), 0xB1, 0xF, 0xF, true)); }
        else if (m == 2) { z0 += __int_as_float(__builtin_amdgcn_update_dpp(0, __float_as_int(z0), 0x4E, 0xF, 0xF, true));
                           z1 += __int_as_float(__builtin_amdgcn_update_dpp(0, __float_as_int(z1), 0x4E, 0xF, 0xF, true));
                           z2 += __int_as_float(__builtin_amdgcn_update_dpp(0, __float_as_int(z2), 0x4E, 0xF, 0xF, true));
                           z3 += __int_as_float(__builtin_amdgcn_update_dpp(0, __float_as_int(z3), 0x4E, 0xF, 0xF, true)); }
        else if (m == 4) { z0 += __int_as_float(__builtin_amdgcn_update_dpp(0, __builtin_amdgcn_update_dpp(0, __float_as_int(z0), 0x1B, 0xF, 0xF, true), 0x141, 0xF, 0xF, true));
                           z1 += __int_as_float(__builtin_amdgcn_update_dpp(0, __builtin_amdgcn_update_dpp(0, __float_as_int(z1), 0x1B, 0xF, 0xF, true), 0x141, 0xF, 0xF, true));
                           z2 += __int_as_float(__builtin_amdgcn_update_dpp(0, __builtin_amdgcn_update_dpp(0, __float_as_int(z2), 0x1B, 0xF, 0xF, true), 0x141, 0xF, 0xF, true));
                           z3 += __int_as_float(__builtin_amdgcn_update_dpp(0, __builtin_amdgcn_update_dpp(0, __float_as_int(z3), 0x1B, 0xF, 0xF, true), 0x141, 0xF, 0xF, true)); }
        else if (m == 8) { z0 += __int_as_float(__builtin_amdgcn_update_dpp(0, __float_as_int(z0), 0x128, 0xF, 0xF, true));
                           z1 += __int_as_float(__builtin_amdgcn_update_dpp(0, __float_as_int(z1), 0x128, 0xF, 0xF, true));
                           z2 += __int_as_float(__builtin_amdgcn_update_dpp(0, __float_as_int(z2), 0x128, 0xF, 0xF, true));
                           z3 += __int_as_float(__builtin_amdgcn_update_dpp(0, __float_as_int(z3), 0x128, 0xF, 0xF, true)); }
        else if (m == 16){ z0 += __int_as_float(__builtin_amdgcn_ds_bpermute(a16, __float_as_int(z0)));
                           z1 += __int_as_float(__builtin_amdgcn_ds_bpermute(a16, __float_as_int(z1)));
                           z2 += __int_as_float(__builtin_amdgcn_ds_bpermute(a16, __float_as_int(z2)));
                           z3 += __int_as_float(__builtin_amdgcn_ds_bpermute(a16, __float_as_int(z3))); }
        else             { z0 += __int_as_float(__builtin_amdgcn_ds_bpermute(a32, __float_as_int(z0)));
                           z1 += __int_as_float(__builtin_amdgcn_ds_bpermute(a32, __float_as_int(z1)));
                           z2 += __int_as_float(__builtin_amdgcn_ds_bpermute(a32, __float_as_int(z2)));
                           z3 += __int_as_float(__builtin_amdgcn_ds_bpermute(a32, __float_as_int(z3))); }
    }
    if (lane == 0) {
        out[wid * 4 + 0] = z0 * oscale[0];
        out[wid * 4 + 1] = z1 * oscale[1];
        out[wid * 4 + 2] = z2 * oscale[2];
        out[wid * 4 + 3] = z3 * oscale[3];
    }
#undef SWAPR
}

extern "C" void kernel_launch(void* const* d_in, const int* in_sizes, int n_in,
                              void* d_out, int out_size, void* d_ws, size_t ws_size,
                              hipStream_t stream) {
    const float* x      = (const float*)d_in[0];
    const float* isc    = (const float*)d_in[1];
    const float* w      = (const float*)d_in[2];
    const float* oscale = (const float*)d_in[3];
    float* out = (float*)d_out;

    const int B = in_sizes[0] / OBS;             // 4096
    const int threads = 256;                     // 4 waves -> 4 samples per block
    const int blocks = (B * 64 + threads - 1) / threads;
    qsim_kernel<<<blocks, threads, 0, stream>>>(x, isc, w, oscale, out, B);
}